// Round 12
// baseline (271.061 us; speedup 1.0000x reference)
//
#include <hip/hip_runtime.h>

#define N_NODES 50000
#define N_EDGES 600000
// feature dims: IN=128, HID=64, OUT=128

typedef float v2f __attribute__((ext_vector_type(2)));
typedef float v4f __attribute__((ext_vector_type(4)));

// ---------------- workspace layout ----------------
#define WF_PA    0            // PA[N][128]: cols 0-63 = a = x@W_nl2, 64-127 = px
#define WF_ES    6400000      // es[N][128] -> 12,800,000
#define WF_UP    12800000     // u_part[N][64] -> 16,000,000
// ints
#define WI_CNT   16000000     // 50000
#define WI_OFF   16050000     // 50000
#define WI_CUR   16100000     // 50000
#define WI_BSUM  16150000     // 256
#define WI_BOFF  16150256     // 256
#define WI_EPAIR 16150512     // int2 x 600000 -> 17,350,512
// small floats
#define WF_T2    17350528     // 4096
#define WF_BEG   17354624     // 128
#define WF_RH    17354752     // 64
#define WF_K1    17354816     // 4096
#define WF_WAX   17358912     // 128*128 -> 17375296
#define WF_WE    17375296     // 128*64  -> 17383488
#define WF_R     17383488     // 128
#define WF_C2    17383616     // 128 -> ends 17,383,744 (~70 MB)

#define NBLK_SCAN 196        // ceil(50000/256)
#define NBLK_E    2344       // ceil(600000/256)
#define NBLK_PT2  17
#define NBLK_K1   16
#define NBLK_WA   97
#define NBLK_PA   391        // ceil(50000/128)

// ---------------- fused launch 1: pre_t2 | zero ----------------
__global__ __launch_bounds__(256) void f1_pret2_zero(
        const float* __restrict__ W2, const float* __restrict__ W_ml,
        const float* __restrict__ b1, const float* __restrict__ b2,
        float* __restrict__ T2, float* __restrict__ be_g,
        int* __restrict__ cnt) {
    int bid = blockIdx.x;
    if (bid < NBLK_PT2) {
        int idx = bid * 256 + threadIdx.x;
        if (idx < 4096) {
            int i = idx >> 6, j = idx & 63;
            float s = 0.f;
            for (int k = 0; k < 128; ++k) s += W2[i*128+k] * W_ml[k*64+j];
            T2[idx] = s;
        } else if (idx < 4224) {
            int j = idx - 4096;
            float s = b2[j];
            for (int k = 0; k < 64; ++k) s += b1[k] * W2[k*128+j];
            be_g[j] = s;
        }
    } else {
        int i = (bid - NBLK_PT2) * 256 + threadIdx.x;
        if (i < N_NODES) cnt[i] = 0;
    }
}

// ---------------- fused launch 2: pre_k1 | hist ----------------
__global__ __launch_bounds__(256) void f2_prek1_hist(
        const float* __restrict__ W1, const float* __restrict__ T2,
        float* __restrict__ K1,
        const int* __restrict__ dst, int* __restrict__ cnt) {
    int bid = blockIdx.x;
    if (bid < NBLK_K1) {
        int idx = bid * 256 + threadIdx.x;
        int i = idx >> 6, j = idx & 63;
        float s = 0.f;
        for (int k = 0; k < 64; ++k) s += W1[i*64+k] * T2[k*64+j];
        K1[idx] = s;
    } else {
        int e = (bid - NBLK_K1) * 256 + threadIdx.x;
        if (e < N_EDGES) atomicAdd(&cnt[dst[e]], 1);
    }
}

// ---------------- fused launch 3: pre_wa | scan_a ----------------
__global__ __launch_bounds__(256) void f3_prewa_scana(
        const float* __restrict__ W_nl1, const float* __restrict__ W_el,
        const float* __restrict__ W_nl2, const float* __restrict__ K1,
        const float* __restrict__ b_nl1, const float* __restrict__ b_el,
        const float* __restrict__ be_g, const float* __restrict__ W_ml,
        float* __restrict__ WAX, float* __restrict__ WE,
        float* __restrict__ rh_g,
        const int* __restrict__ cnt, int* __restrict__ bsum) {
    int bid = blockIdx.x;
    if (bid < NBLK_WA) {
        int idx = bid * 256 + threadIdx.x;
        if (idx < 16384) {
            int i = idx >> 7, j = idx & 127;
            if (j < 64) {
                WAX[idx] = W_nl2[i*64+j];
            } else {
                float s = 0.f;
                for (int k = 0; k < 64; ++k) s += W_nl1[i*64+k] * K1[k*64+(j-64)];
                WAX[idx] = s;
            }
        } else if (idx < 24576) {
            int p = idx - 16384; int i = p >> 6, j = p & 63;
            float s = 0.f;
            for (int k = 0; k < 64; ++k) s += W_el[i*64+k] * K1[k*64+j];
            WE[p] = s;
        } else if (idx < 24640) {
            int t = idx - 24576;
            float s = 0.f;
            for (int k = 0; k < 64; ++k)  s += (b_nl1[k] + b_el[k]) * K1[k*64+t];
            for (int k = 0; k < 128; ++k) s += be_g[k] * W_ml[k*64+t];
            rh_g[t] = s;
        }
    } else {
        __shared__ int s[256];
        int blk = bid - NBLK_WA;
        int i = blk * 256 + threadIdx.x;
        int v = (i < N_NODES) ? cnt[i] : 0;
        s[threadIdx.x] = v;
        __syncthreads();
        for (int d = 128; d > 0; d >>= 1) {
            if (threadIdx.x < d) s[threadIdx.x] += s[threadIdx.x + d];
            __syncthreads();
        }
        if (threadIdx.x == 0) bsum[blk] = s[0];
    }
}

// ---------------- fused launch 4: pre_rc | scan_b ----------------
__global__ __launch_bounds__(256) void f4_prerc_scanb(
        const float* __restrict__ rh_g, const float* __restrict__ W_em,
        const float* __restrict__ b_nl2, const float* __restrict__ b_ml,
        const float* __restrict__ b_em,
        float* __restrict__ r, float* __restrict__ c2,
        const int* __restrict__ bsum, int* __restrict__ boff) {
    int t = threadIdx.x;
    if (blockIdx.x == 0) {
        if (t < 128) {
            float s = 0.f;
            for (int k = 0; k < 64; ++k) s += rh_g[k] * W_em[k*128+t];
            r[t] = s;
        } else {
            int j = t - 128;
            float s = b_em[j];
            for (int k = 0; k < 64; ++k) s += (b_nl2[k] + b_ml[k]) * W_em[k*128+j];
            c2[j] = s;
        }
    } else {
        __shared__ int s[256];
        int v = (t < NBLK_SCAN) ? bsum[t] : 0;
        s[t] = v;
        __syncthreads();
        for (int d = 1; d < 256; d <<= 1) {
            int tv = (t >= d) ? s[t - d] : 0;
            __syncthreads();
            s[t] += tv;
            __syncthreads();
        }
        if (t < NBLK_SCAN) boff[t] = s[t] - v;   // exclusive
    }
}

// ---------------- scan_c (proven) ----------------
__global__ __launch_bounds__(256) void scan_c_kernel(const int* __restrict__ cnt,
                                                     const int* __restrict__ boff,
                                                     int* __restrict__ offs,
                                                     int* __restrict__ cursor) {
    __shared__ int s[256];
    int i = blockIdx.x * 256 + threadIdx.x;
    int t = threadIdx.x;
    int v = (i < N_NODES) ? cnt[i] : 0;
    s[t] = v;
    __syncthreads();
    for (int d = 1; d < 256; d <<= 1) {
        int tv = (t >= d) ? s[t - d] : 0;
        __syncthreads();
        s[t] += tv;
        __syncthreads();
    }
    if (i < N_NODES) {
        int ex = s[t] - v + boff[blockIdx.x];
        offs[i] = ex;
        cursor[i] = ex;
    }
}

// ---------------- fused launch 6: fill | pa ----------------
// fill: epair[pos] = (e, src[e]) bucketed by dst.  pa: PA = x@WAX (proven tile)
__global__ __launch_bounds__(256) void f5_fill_pa(
        const int* __restrict__ dst, const int* __restrict__ src,
        int* __restrict__ cursor, int2* __restrict__ epair,
        const float* __restrict__ x, const float* __restrict__ WAX,
        float* __restrict__ PA) {
    int bid = blockIdx.x;
    if (bid < NBLK_E) {
        int e = bid * 256 + threadIdx.x;
        if (e < N_EDGES) {
            int pos = atomicAdd(&cursor[dst[e]], 1);
            epair[pos] = make_int2(e, src[e]);
        }
        return;
    }
    __shared__ float As[32][133];
    __shared__ float Ws[32][128];
    int base = (bid - NBLK_E) * 128;
    int t = threadIdx.x;
    int cg = t & 15, rg = t >> 4;
    int c0 = cg * 8, r0 = rg * 8;

    float acc[8][8];
    #pragma unroll
    for (int i = 0; i < 8; ++i)
        #pragma unroll
        for (int j = 0; j < 8; ++j) acc[i][j] = 0.f;

    int arow0 = t >> 3;
    int akq   = t & 7;

    for (int k0 = 0; k0 < 128; k0 += 32) {
        __syncthreads();
        #pragma unroll
        for (int i = 0; i < 4; ++i) {
            int row = arow0 + i * 32;
            int n = base + row;
            float4 v = make_float4(0.f, 0.f, 0.f, 0.f);
            if (n < N_NODES)
                v = *(const float4*)&x[(size_t)n * 128 + k0 + akq * 4];
            As[akq * 4 + 0][row] = v.x;
            As[akq * 4 + 1][row] = v.y;
            As[akq * 4 + 2][row] = v.z;
            As[akq * 4 + 3][row] = v.w;
        }
        #pragma unroll
        for (int i = 0; i < 4; ++i) {
            int idx = t + i * 256;
            int row = idx >> 5, q4 = idx & 31;
            *(float4*)&Ws[row][q4 * 4] =
                *(const float4*)&WAX[(size_t)(k0 + row) * 128 + q4 * 4];
        }
        __syncthreads();
        #pragma unroll 8
        for (int k = 0; k < 32; ++k) {
            float a[8], w[8];
            *(float4*)&a[0] = *(const float4*)&As[k][r0];
            *(float4*)&a[4] = *(const float4*)&As[k][r0 + 4];
            *(float4*)&w[0] = *(const float4*)&Ws[k][c0];
            *(float4*)&w[4] = *(const float4*)&Ws[k][c0 + 4];
            #pragma unroll
            for (int i = 0; i < 8; ++i)
                #pragma unroll
                for (int jj = 0; jj < 8; ++jj)
                    acc[i][jj] += a[i] * w[jj];
        }
    }

    #pragma unroll
    for (int i = 0; i < 8; ++i) {
        int n = base + r0 + i;
        if (n < N_NODES) {
            *(float4*)&PA[(size_t)n * 128 + c0]     = *(float4*)&acc[i][0];
            *(float4*)&PA[(size_t)n * 128 + c0 + 4] = *(float4*)&acc[i][4];
        }
    }
}

// ---------------- gather (R11, byte-identical; proven local optimum) ----------
__global__ __launch_bounds__(256) void gather_kernel(
        const float* __restrict__ PA, const float* __restrict__ ef,
        const int* __restrict__ cnt, const int* __restrict__ offs,
        const int2* __restrict__ epair,
        float* __restrict__ es, float* __restrict__ u_part) {
    int n    = (int)((blockIdx.x * 256 + threadIdx.x) >> 6);
    int lane = threadIdx.x & 63;
    if (n >= N_NODES) return;
    int off = offs[n], deg = cnt[n];
    int half = lane >> 5;
    int hl   = lane & 31;
    int ce4  = hl * 4;
    int cp2  = hl * 2;
    float ae0 = 0.f, ae1 = 0.f, ae2 = 0.f, ae3 = 0.f;
    float ap0 = 0.f, ap1 = 0.f;
    for (int c0 = 0; c0 < deg; c0 += 64) {
        int j = c0 + lane;
        int2 p = make_int2(0, 0);
        if (j < deg) p = epair[off + j];
        int m = deg - c0; if (m > 64) m = 64;
        for (int j2 = 0; j2 < m; j2 += 8) {
            v4f ev[4]; v2f pv[4]; float msk[4];
            #pragma unroll
            for (int q = 0; q < 4; ++q) {
                int jj = j2 + q * 2 + half;
                int idx = (jj < m) ? jj : (m - 1);
                msk[q] = (jj < m) ? 1.f : 0.f;
                int e_ = __shfl(p.x, idx);
                int s_ = __shfl(p.y, idx);
                ev[q] = __builtin_nontemporal_load(
                            (const v4f*)(ef + (size_t)e_ * 128 + ce4));
                pv[q] = *(const v2f*)(PA + (size_t)s_ * 128 + 64 + cp2);
            }
            #pragma unroll
            for (int q = 0; q < 4; ++q) {
                ae0 += msk[q] * ev[q][0];
                ae1 += msk[q] * ev[q][1];
                ae2 += msk[q] * ev[q][2];
                ae3 += msk[q] * ev[q][3];
                ap0 += msk[q] * pv[q][0];
                ap1 += msk[q] * pv[q][1];
            }
        }
    }
    ae0 += __shfl_xor(ae0, 32);
    ae1 += __shfl_xor(ae1, 32);
    ae2 += __shfl_xor(ae2, 32);
    ae3 += __shfl_xor(ae3, 32);
    ap0 += __shfl_xor(ap0, 32);
    ap1 += __shfl_xor(ap1, 32);
    if (half == 0) {
        *(float4*)&es[(size_t)n * 128 + ce4] = make_float4(ae0, ae1, ae2, ae3);
    } else {
        float2 av = *(const float2*)&PA[(size_t)n * 128 + cp2];
        *(float2*)&u_part[(size_t)n * 64 + cp2] = make_float2(av.x + ap0, av.y + ap1);
    }
}

// ---------------- gemm12: out = (u_part + es@WE) @ W_em + deg*r + c2 ----------
// 64-node tile. Phase A: U[64][64] in regs (4x4/thread). Phase B: U->LDS^T,
// out[64][128] (4x8/thread). LDS union: max(17 KB, 49.3 KB).
__global__ __launch_bounds__(256) void gemm12_kernel(
        const float* __restrict__ es, const float* __restrict__ u_part,
        const float* __restrict__ WE, const int* __restrict__ cnt,
        const float* __restrict__ W_em,
        const float* __restrict__ rvec, const float* __restrict__ c2,
        float* __restrict__ out) {
    __shared__ union SM {
        struct { float As[32][69]; float Ws[32][64]; } a;
        struct { float UsT[64][69]; float Wem[64][128]; } b;
    } sm;
    int base = blockIdx.x * 64;
    int t = threadIdx.x;
    int cg = t & 15, rg = t >> 4;

    // ---- phase A: U = u_part + es @ WE  (rows r0a.., cols c0a..) ----
    int c0a = cg * 4, r0a = rg * 4;
    float accA[4][4];
    #pragma unroll
    for (int i = 0; i < 4; ++i) {
        int n = base + r0a + i;
        float4 pv = make_float4(0.f, 0.f, 0.f, 0.f);
        if (n < N_NODES) pv = *(const float4*)&u_part[(size_t)n * 64 + c0a];
        accA[i][0] = pv.x; accA[i][1] = pv.y; accA[i][2] = pv.z; accA[i][3] = pv.w;
    }

    for (int k0 = 0; k0 < 128; k0 += 32) {
        __syncthreads();
        // stage es^T chunk: 64 rows x 32 k = 512 float4
        #pragma unroll
        for (int i = 0; i < 2; ++i) {
            int idx = t + i * 256;
            int row = idx >> 3, kq = idx & 7;
            int n = base + row;
            float4 v = make_float4(0.f, 0.f, 0.f, 0.f);
            if (n < N_NODES)
                v = *(const float4*)&es[(size_t)n * 128 + k0 + kq * 4];
            sm.a.As[kq * 4 + 0][row] = v.x;
            sm.a.As[kq * 4 + 1][row] = v.y;
            sm.a.As[kq * 4 + 2][row] = v.z;
            sm.a.As[kq * 4 + 3][row] = v.w;
        }
        // stage WE chunk: 32 k x 64 c = 512 float4
        #pragma unroll
        for (int i = 0; i < 2; ++i) {
            int idx = t + i * 256;
            int row = idx >> 4, q4 = idx & 15;
            *(float4*)&sm.a.Ws[row][q4 * 4] =
                *(const float4*)&WE[(size_t)(k0 + row) * 64 + q4 * 4];
        }
        __syncthreads();
        #pragma unroll 8
        for (int k = 0; k < 32; ++k) {
            float a[4], w[4];
            *(float4*)&a[0] = *(const float4*)&sm.a.As[k][r0a];
            *(float4*)&w[0] = *(const float4*)&sm.a.Ws[k][c0a];
            #pragma unroll
            for (int i = 0; i < 4; ++i)
                #pragma unroll
                for (int j = 0; j < 4; ++j)
                    accA[i][j] += a[i] * w[j];
        }
    }

    // ---- phase B: out = U @ W_em + deg*r + c2 ----
    __syncthreads();   // phase A reads done; union may be overwritten
    // U^T into LDS: thread holds rows r0a.., cols c0a..  -> UsT[col][row]
    #pragma unroll
    for (int j = 0; j < 4; ++j)
        #pragma unroll
        for (int i = 0; i < 4; ++i)
            sm.b.UsT[c0a + j][r0a + i] = accA[i][j];
    // stage W_em: 64x128 = 2048 float4
    #pragma unroll
    for (int i = 0; i < 8; ++i) {
        int idx = t + i * 256;
        int row = idx >> 5, q4 = idx & 31;
        *(float4*)&sm.b.Wem[row][q4 * 4] =
            *(const float4*)&W_em[(size_t)row * 128 + q4 * 4];
    }

    int c0b = cg * 8, r0b = rg * 4;
    float4 rva = *(const float4*)&rvec[c0b];
    float4 rvb = *(const float4*)&rvec[c0b + 4];
    float4 cva = *(const float4*)&c2[c0b];
    float4 cvb = *(const float4*)&c2[c0b + 4];
    float accB[4][8];
    #pragma unroll
    for (int i = 0; i < 4; ++i) {
        int n = base + r0b + i;
        float dg = (n < N_NODES) ? (float)cnt[n] : 0.f;
        accB[i][0] = cva.x + dg * rva.x;  accB[i][1] = cva.y + dg * rva.y;
        accB[i][2] = cva.z + dg * rva.z;  accB[i][3] = cva.w + dg * rva.w;
        accB[i][4] = cvb.x + dg * rvb.x;  accB[i][5] = cvb.y + dg * rvb.y;
        accB[i][6] = cvb.z + dg * rvb.z;  accB[i][7] = cvb.w + dg * rvb.w;
    }
    __syncthreads();

    #pragma unroll 8
    for (int k = 0; k < 64; ++k) {
        float a[4], w[8];
        *(float4*)&a[0] = *(const float4*)&sm.b.UsT[k][r0b];
        *(float4*)&w[0] = *(const float4*)&sm.b.Wem[k][c0b];
        *(float4*)&w[4] = *(const float4*)&sm.b.Wem[k][c0b + 4];
        #pragma unroll
        for (int i = 0; i < 4; ++i)
            #pragma unroll
            for (int j = 0; j < 8; ++j)
                accB[i][j] += a[i] * w[j];
    }

    #pragma unroll
    for (int i = 0; i < 4; ++i) {
        int n = base + r0b + i;
        if (n < N_NODES) {
            *(float4*)&out[(size_t)n * 128 + c0b]     = *(float4*)&accB[i][0];
            *(float4*)&out[(size_t)n * 128 + c0b + 4] = *(float4*)&accB[i][4];
        }
    }
}

extern "C" void kernel_launch(void* const* d_in, const int* in_sizes, int n_in,
                              void* d_out, int out_size, void* d_ws, size_t ws_size,
                              hipStream_t stream) {
    const float* x     = (const float*)d_in[0];
    const float* ef    = (const float*)d_in[1];
    const int*   src   = (const int*)d_in[2];
    const int*   dst   = (const int*)d_in[3];
    const float* W_nl1 = (const float*)d_in[4];
    const float* b_nl1 = (const float*)d_in[5];
    const float* W_el  = (const float*)d_in[6];
    const float* b_el  = (const float*)d_in[7];
    const float* W1    = (const float*)d_in[8];
    const float* b1    = (const float*)d_in[9];
    const float* W2    = (const float*)d_in[10];
    const float* b2    = (const float*)d_in[11];
    const float* W_nl2 = (const float*)d_in[12];
    const float* b_nl2 = (const float*)d_in[13];
    const float* W_ml  = (const float*)d_in[14];
    const float* b_ml  = (const float*)d_in[15];
    const float* W_em  = (const float*)d_in[16];
    const float* b_em  = (const float*)d_in[17];

    int*   wsI = (int*)d_ws;
    float* wsF = (float*)d_ws;
    float* PA     = wsF + WF_PA;
    float* es     = wsF + WF_ES;
    float* u_part = wsF + WF_UP;
    int*   cnt    = wsI + WI_CNT;
    int*   offs   = wsI + WI_OFF;
    int*   cursor = wsI + WI_CUR;
    int*   bsum   = wsI + WI_BSUM;
    int*   boff   = wsI + WI_BOFF;
    int2*  epair  = (int2*)(wsI + WI_EPAIR);
    float* T2   = wsF + WF_T2;
    float* be_g = wsF + WF_BEG;
    float* rh_g = wsF + WF_RH;
    float* K1   = wsF + WF_K1;
    float* WAX  = wsF + WF_WAX;
    float* WE   = wsF + WF_WE;
    float* r    = wsF + WF_R;
    float* c2   = wsF + WF_C2;

    f1_pret2_zero<<<NBLK_PT2 + NBLK_SCAN, 256, 0, stream>>>(
        W2, W_ml, b1, b2, T2, be_g, cnt);
    f2_prek1_hist<<<NBLK_K1 + NBLK_E, 256, 0, stream>>>(W1, T2, K1, dst, cnt);
    f3_prewa_scana<<<NBLK_WA + NBLK_SCAN, 256, 0, stream>>>(
        W_nl1, W_el, W_nl2, K1, b_nl1, b_el, be_g, W_ml, WAX, WE, rh_g,
        cnt, bsum);
    f4_prerc_scanb<<<2, 256, 0, stream>>>(
        rh_g, W_em, b_nl2, b_ml, b_em, r, c2, bsum, boff);
    scan_c_kernel<<<NBLK_SCAN, 256, 0, stream>>>(cnt, boff, offs, cursor);
    f5_fill_pa<<<NBLK_E + NBLK_PA, 256, 0, stream>>>(
        dst, src, cursor, epair, x, WAX, PA);

    gather_kernel<<<(N_NODES + 3) / 4, 256, 0, stream>>>(
        PA, ef, cnt, offs, epair, es, u_part);

    gemm12_kernel<<<(N_NODES + 63) / 64, 256, 0, stream>>>(
        es, u_part, WE, cnt, W_em, r, c2, (float*)d_out);
}

// Round 13
// 247.263 us; speedup vs baseline: 1.0962x; 1.0962x over previous
//
#include <hip/hip_runtime.h>

#define N_NODES 50000
#define N_EDGES 600000
// feature dims: IN=128, HID=64, OUT=128

typedef float v2f __attribute__((ext_vector_type(2)));
typedef float v4f __attribute__((ext_vector_type(4)));

// ---------------- workspace layout ----------------
#define WF_PA    0            // PA[N][128]: cols 0-63 = a = x@W_nl2, 64-127 = px
#define WF_ES    6400000      // es[N][128] -> 12,800,000
#define WF_UP    12800000     // u_part[N][64] -> 16,000,000
#define WF_UN    16000000     // u[N][64] -> 19,200,000
// ints
#define WI_CNT   19200000     // 50000
#define WI_OFF   19250000     // 50000
#define WI_CUR   19300000     // 50000
#define WI_BSUM  19350000     // 256
#define WI_BOFF  19350256     // 256
#define WI_EPAIR 19350512     // int2 x 600000 -> 20,550,512
// small floats
#define WF_T2    20550528     // 4096
#define WF_BEG   20554624     // 128
#define WF_RH    20554752     // 64
#define WF_K1    20554816     // 4096
#define WF_WAX   20558912     // 128*128 -> 20575296
#define WF_WE    20575296     // 128*64  -> 20583488
#define WF_R     20583488     // 128
#define WF_C2    20583616     // 128 -> ends 20,583,744 (~82 MB)

#define NBLK_SCAN 196        // ceil(50000/256)

// ---------------- precompute chain (global-staged, proven) ----------------
__global__ __launch_bounds__(256) void pre_t2_kernel(
        const float* __restrict__ W2, const float* __restrict__ W_ml,
        const float* __restrict__ b1, const float* __restrict__ b2,
        float* __restrict__ T2, float* __restrict__ be_g) {
    int idx = blockIdx.x * 256 + threadIdx.x;
    if (idx < 4096) {
        int i = idx >> 6, j = idx & 63;
        float s = 0.f;
        for (int k = 0; k < 128; ++k) s += W2[i*128+k] * W_ml[k*64+j];
        T2[idx] = s;
    } else if (idx < 4224) {
        int j = idx - 4096;
        float s = b2[j];
        for (int k = 0; k < 64; ++k) s += b1[k] * W2[k*128+j];
        be_g[j] = s;
    }
}

__global__ __launch_bounds__(256) void pre_k1_kernel(
        const float* __restrict__ W1, const float* __restrict__ T2,
        float* __restrict__ K1) {
    int idx = blockIdx.x * 256 + threadIdx.x;
    if (idx >= 4096) return;
    int i = idx >> 6, j = idx & 63;
    float s = 0.f;
    for (int k = 0; k < 64; ++k) s += W1[i*64+k] * T2[k*64+j];
    K1[idx] = s;
}

// WAX[i][j] = j<64 ? W_nl2[i][j] : (W_nl1@K1)[i][j-64]; WE = W_el@K1; rh
__global__ __launch_bounds__(256) void pre_wa_kernel(
        const float* __restrict__ W_nl1, const float* __restrict__ W_el,
        const float* __restrict__ W_nl2, const float* __restrict__ K1,
        const float* __restrict__ b_nl1, const float* __restrict__ b_el,
        const float* __restrict__ be_g, const float* __restrict__ W_ml,
        float* __restrict__ WAX, float* __restrict__ WE,
        float* __restrict__ rh_g) {
    int idx = blockIdx.x * 256 + threadIdx.x;
    if (idx < 16384) {
        int i = idx >> 7, j = idx & 127;
        if (j < 64) {
            WAX[idx] = W_nl2[i*64+j];
        } else {
            float s = 0.f;
            for (int k = 0; k < 64; ++k) s += W_nl1[i*64+k] * K1[k*64+(j-64)];
            WAX[idx] = s;
        }
    } else if (idx < 24576) {
        int p = idx - 16384; int i = p >> 6, j = p & 63;
        float s = 0.f;
        for (int k = 0; k < 64; ++k) s += W_el[i*64+k] * K1[k*64+j];
        WE[p] = s;
    } else if (idx < 24640) {
        int t = idx - 24576;
        float s = 0.f;
        for (int k = 0; k < 64; ++k)  s += (b_nl1[k] + b_el[k]) * K1[k*64+t];
        for (int k = 0; k < 128; ++k) s += be_g[k] * W_ml[k*64+t];
        rh_g[t] = s;
    }
}

__global__ __launch_bounds__(256) void pre_rc_kernel(
        const float* __restrict__ rh_g, const float* __restrict__ W_em,
        const float* __restrict__ b_nl2, const float* __restrict__ b_ml,
        const float* __restrict__ b_em,
        float* __restrict__ r, float* __restrict__ c2) {
    int idx = threadIdx.x;
    if (idx < 128) {
        float s = 0.f;
        for (int k = 0; k < 64; ++k) s += rh_g[k] * W_em[k*128+idx];
        r[idx] = s;
    } else {
        int j = idx - 128;
        float s = b_em[j];
        for (int k = 0; k < 64; ++k) s += (b_nl2[k] + b_ml[k]) * W_em[k*128+j];
        c2[j] = s;
    }
}

// ---------------- CSR build (proven) ----------------
__global__ __launch_bounds__(256) void zero_kernel(int* __restrict__ cnt) {
    int i = blockIdx.x * 256 + threadIdx.x;
    if (i < N_NODES) cnt[i] = 0;
}

__global__ __launch_bounds__(256) void hist_kernel(const int* __restrict__ dst,
                                                   int* __restrict__ cnt) {
    int e = blockIdx.x * 256 + threadIdx.x;
    if (e < N_EDGES) atomicAdd(&cnt[dst[e]], 1);
}

__global__ __launch_bounds__(256) void scan_a_kernel(const int* __restrict__ cnt,
                                                     int* __restrict__ bsum) {
    __shared__ int s[256];
    int i = blockIdx.x * 256 + threadIdx.x;
    int v = (i < N_NODES) ? cnt[i] : 0;
    s[threadIdx.x] = v;
    __syncthreads();
    for (int d = 128; d > 0; d >>= 1) {
        if (threadIdx.x < d) s[threadIdx.x] += s[threadIdx.x + d];
        __syncthreads();
    }
    if (threadIdx.x == 0) bsum[blockIdx.x] = s[0];
}

__global__ __launch_bounds__(256) void scan_b_kernel(const int* __restrict__ bsum,
                                                     int* __restrict__ boff) {
    __shared__ int s[256];
    int t = threadIdx.x;
    int v = (t < NBLK_SCAN) ? bsum[t] : 0;
    s[t] = v;
    __syncthreads();
    for (int d = 1; d < 256; d <<= 1) {
        int tv = (t >= d) ? s[t - d] : 0;
        __syncthreads();
        s[t] += tv;
        __syncthreads();
    }
    if (t < NBLK_SCAN) boff[t] = s[t] - v;   // exclusive
}

__global__ __launch_bounds__(256) void scan_c_kernel(const int* __restrict__ cnt,
                                                     const int* __restrict__ boff,
                                                     int* __restrict__ offs,
                                                     int* __restrict__ cursor) {
    __shared__ int s[256];
    int i = blockIdx.x * 256 + threadIdx.x;
    int t = threadIdx.x;
    int v = (i < N_NODES) ? cnt[i] : 0;
    s[t] = v;
    __syncthreads();
    for (int d = 1; d < 256; d <<= 1) {
        int tv = (t >= d) ? s[t - d] : 0;
        __syncthreads();
        s[t] += tv;
        __syncthreads();
    }
    if (i < N_NODES) {
        int ex = s[t] - v + boff[blockIdx.x];
        offs[i] = ex;
        cursor[i] = ex;
    }
}

// fill packed (eid, src[eid]) pairs bucketed by dst
__global__ __launch_bounds__(256) void fill_kernel(const int* __restrict__ dst,
                                                   const int* __restrict__ src,
                                                   int* __restrict__ cursor,
                                                   int2* __restrict__ epair) {
    int e = blockIdx.x * 256 + threadIdx.x;
    if (e < N_EDGES) {
        int pos = atomicAdd(&cursor[dst[e]], 1);
        epair[pos] = make_int2(e, src[e]);
    }
}

// ---------------- PA = x @ WAX   [N,128], K=128 (proven 128x128 template) ------
__global__ __launch_bounds__(256) void pa_kernel(
        const float* __restrict__ x, const float* __restrict__ WAX,
        float* __restrict__ PA) {
    __shared__ float As[32][133];
    __shared__ float Ws[32][128];
    int base = blockIdx.x * 128;
    int t = threadIdx.x;
    int cg = t & 15, rg = t >> 4;
    int c0 = cg * 8, r0 = rg * 8;

    float acc[8][8];
    #pragma unroll
    for (int i = 0; i < 8; ++i)
        #pragma unroll
        for (int j = 0; j < 8; ++j) acc[i][j] = 0.f;

    int arow0 = t >> 3;
    int akq   = t & 7;

    for (int k0 = 0; k0 < 128; k0 += 32) {
        __syncthreads();
        #pragma unroll
        for (int i = 0; i < 4; ++i) {
            int row = arow0 + i * 32;
            int n = base + row;
            float4 v = make_float4(0.f, 0.f, 0.f, 0.f);
            if (n < N_NODES)
                v = *(const float4*)&x[(size_t)n * 128 + k0 + akq * 4];
            As[akq * 4 + 0][row] = v.x;
            As[akq * 4 + 1][row] = v.y;
            As[akq * 4 + 2][row] = v.z;
            As[akq * 4 + 3][row] = v.w;
        }
        #pragma unroll
        for (int i = 0; i < 4; ++i) {
            int idx = t + i * 256;
            int row = idx >> 5, q4 = idx & 31;
            *(float4*)&Ws[row][q4 * 4] =
                *(const float4*)&WAX[(size_t)(k0 + row) * 128 + q4 * 4];
        }
        __syncthreads();
        #pragma unroll 8
        for (int k = 0; k < 32; ++k) {
            float a[8], w[8];
            *(float4*)&a[0] = *(const float4*)&As[k][r0];
            *(float4*)&a[4] = *(const float4*)&As[k][r0 + 4];
            *(float4*)&w[0] = *(const float4*)&Ws[k][c0];
            *(float4*)&w[4] = *(const float4*)&Ws[k][c0 + 4];
            #pragma unroll
            for (int i = 0; i < 8; ++i)
                #pragma unroll
                for (int jj = 0; jj < 8; ++jj)
                    acc[i][jj] += a[i] * w[jj];
        }
    }

    #pragma unroll
    for (int i = 0; i < 8; ++i) {
        int n = base + r0 + i;
        if (n < N_NODES) {
            *(float4*)&PA[(size_t)n * 128 + c0]     = *(float4*)&acc[i][0];
            *(float4*)&PA[(size_t)n * 128 + c0 + 4] = *(float4*)&acc[i][4];
        }
    }
}

// ---------------- gather: es[n] = sum ef[e]; u_part[n] = a[n] + sum px[src] ----
// One wave per node, split into two half-waves, each handling one edge of a
// pair per load inst: ef dwordx4 x 32 lanes (full 512B row / inst), px
// dwordx2 x 32 lanes. Combine halves via shfl_xor(32) at the end.
__global__ __launch_bounds__(256) void gather_kernel(
        const float* __restrict__ PA, const float* __restrict__ ef,
        const int* __restrict__ cnt, const int* __restrict__ offs,
        const int2* __restrict__ epair,
        float* __restrict__ es, float* __restrict__ u_part) {
    int n    = (int)((blockIdx.x * 256 + threadIdx.x) >> 6);
    int lane = threadIdx.x & 63;
    if (n >= N_NODES) return;
    int off = offs[n], deg = cnt[n];
    int half = lane >> 5;        // which edge of the pair this half-wave takes
    int hl   = lane & 31;
    int ce4  = hl * 4;           // ef col base (float4)
    int cp2  = hl * 2;           // px col base (float2)
    float ae0 = 0.f, ae1 = 0.f, ae2 = 0.f, ae3 = 0.f;
    float ap0 = 0.f, ap1 = 0.f;
    for (int c0 = 0; c0 < deg; c0 += 64) {
        int j = c0 + lane;
        int2 p = make_int2(0, 0);
        if (j < deg) p = epair[off + j];
        int m = deg - c0; if (m > 64) m = 64;
        for (int j2 = 0; j2 < m; j2 += 8) {
            v4f ev[4]; v2f pv[4]; float msk[4];
            #pragma unroll
            for (int q = 0; q < 4; ++q) {
                int jj = j2 + q * 2 + half;
                int idx = (jj < m) ? jj : (m - 1);
                msk[q] = (jj < m) ? 1.f : 0.f;
                int e_ = __shfl(p.x, idx);
                int s_ = __shfl(p.y, idx);
                ev[q] = __builtin_nontemporal_load(
                            (const v4f*)(ef + (size_t)e_ * 128 + ce4));
                pv[q] = *(const v2f*)(PA + (size_t)s_ * 128 + 64 + cp2);
            }
            #pragma unroll
            for (int q = 0; q < 4; ++q) {
                ae0 += msk[q] * ev[q][0];
                ae1 += msk[q] * ev[q][1];
                ae2 += msk[q] * ev[q][2];
                ae3 += msk[q] * ev[q][3];
                ap0 += msk[q] * pv[q][0];
                ap1 += msk[q] * pv[q][1];
            }
        }
    }
    // combine the two halves
    ae0 += __shfl_xor(ae0, 32);
    ae1 += __shfl_xor(ae1, 32);
    ae2 += __shfl_xor(ae2, 32);
    ae3 += __shfl_xor(ae3, 32);
    ap0 += __shfl_xor(ap0, 32);
    ap1 += __shfl_xor(ap1, 32);
    if (half == 0) {
        *(float4*)&es[(size_t)n * 128 + ce4] = make_float4(ae0, ae1, ae2, ae3);
    } else {
        float2 av = *(const float2*)&PA[(size_t)n * 128 + cp2];   // a = x@W_nl2
        *(float2*)&u_part[(size_t)n * 64 + cp2] = make_float2(av.x + ap0, av.y + ap1);
    }
}

// ---------------- gemm1: u = u_part + es @ WE   [N,64], K=128 ----------------
__global__ __launch_bounds__(256) void gemm1_kernel(
        const float* __restrict__ es, const float* __restrict__ u_part,
        const float* __restrict__ WE, float* __restrict__ u) {
    __shared__ float As[32][133];
    __shared__ float Ws[32][64];
    int base = blockIdx.x * 128;
    int t = threadIdx.x;
    int cg = t & 15, rg = t >> 4;
    int c0 = cg * 4, r0 = rg * 8;

    float acc[8][4];
    #pragma unroll
    for (int i = 0; i < 8; ++i) {
        int n = base + r0 + i;
        float4 pv = make_float4(0.f, 0.f, 0.f, 0.f);
        if (n < N_NODES) pv = *(const float4*)&u_part[(size_t)n * 64 + c0];
        acc[i][0] = pv.x; acc[i][1] = pv.y; acc[i][2] = pv.z; acc[i][3] = pv.w;
    }

    int arow0 = t >> 3;
    int akq   = t & 7;

    for (int k0 = 0; k0 < 128; k0 += 32) {
        __syncthreads();
        #pragma unroll
        for (int i = 0; i < 4; ++i) {
            int row = arow0 + i * 32;
            int n = base + row;
            float4 v = make_float4(0.f, 0.f, 0.f, 0.f);
            if (n < N_NODES)
                v = *(const float4*)&es[(size_t)n * 128 + k0 + akq * 4];
            As[akq * 4 + 0][row] = v.x;
            As[akq * 4 + 1][row] = v.y;
            As[akq * 4 + 2][row] = v.z;
            As[akq * 4 + 3][row] = v.w;
        }
        #pragma unroll
        for (int i = 0; i < 2; ++i) {
            int idx = t + i * 256;
            int row = idx >> 4, q4 = idx & 15;
            *(float4*)&Ws[row][q4 * 4] =
                *(const float4*)&WE[(size_t)(k0 + row) * 64 + q4 * 4];
        }
        __syncthreads();
        #pragma unroll 8
        for (int k = 0; k < 32; ++k) {
            float a[8];
            *(float4*)&a[0] = *(const float4*)&As[k][r0];
            *(float4*)&a[4] = *(const float4*)&As[k][r0 + 4];
            float4 w = *(const float4*)&Ws[k][c0];
            #pragma unroll
            for (int i = 0; i < 8; ++i) {
                acc[i][0] += a[i] * w.x;
                acc[i][1] += a[i] * w.y;
                acc[i][2] += a[i] * w.z;
                acc[i][3] += a[i] * w.w;
            }
        }
    }

    #pragma unroll
    for (int i = 0; i < 8; ++i) {
        int n = base + r0 + i;
        if (n < N_NODES)
            *(float4*)&u[(size_t)n * 64 + c0] = *(float4*)&acc[i][0];
    }
}

// ---------------- gemm2: out = u @ W_em + deg*r + c2   [N,128], K=64 (proven) --
__global__ __launch_bounds__(256) void gemm2_kernel(
        const float* __restrict__ u, const int* __restrict__ cnt,
        const float* __restrict__ W_em,
        const float* __restrict__ rvec, const float* __restrict__ c2,
        float* __restrict__ out) {
    __shared__ float UsT[64][69];
    __shared__ float Wem[64][128];
    int base = blockIdx.x * 64;
    int t = threadIdx.x;
    int cg = t & 15, rg = t >> 4;
    int c0 = cg * 8, r0 = rg * 4;

    #pragma unroll
    for (int i = 0; i < 4; ++i) {
        int idx = t + i * 256;
        int row = idx >> 4, kq = idx & 15;
        int n = base + row;
        float4 v = make_float4(0.f, 0.f, 0.f, 0.f);
        if (n < N_NODES) v = *(const float4*)&u[(size_t)n * 64 + kq * 4];
        UsT[kq * 4 + 0][row] = v.x;
        UsT[kq * 4 + 1][row] = v.y;
        UsT[kq * 4 + 2][row] = v.z;
        UsT[kq * 4 + 3][row] = v.w;
    }
    #pragma unroll
    for (int i = 0; i < 8; ++i) {
        int idx = t + i * 256;
        int row = idx >> 5, q4 = idx & 31;
        *(float4*)&Wem[row][q4 * 4] = *(const float4*)&W_em[(size_t)row * 128 + q4 * 4];
    }

    float4 rva = *(const float4*)&rvec[c0];
    float4 rvb = *(const float4*)&rvec[c0 + 4];
    float4 cva = *(const float4*)&c2[c0];
    float4 cvb = *(const float4*)&c2[c0 + 4];
    float acc[4][8];
    #pragma unroll
    for (int i = 0; i < 4; ++i) {
        int n = base + r0 + i;
        float dg = (n < N_NODES) ? (float)cnt[n] : 0.f;
        acc[i][0] = cva.x + dg * rva.x;  acc[i][1] = cva.y + dg * rva.y;
        acc[i][2] = cva.z + dg * rva.z;  acc[i][3] = cva.w + dg * rva.w;
        acc[i][4] = cvb.x + dg * rvb.x;  acc[i][5] = cvb.y + dg * rvb.y;
        acc[i][6] = cvb.z + dg * rvb.z;  acc[i][7] = cvb.w + dg * rvb.w;
    }
    __syncthreads();

    #pragma unroll 8
    for (int k = 0; k < 64; ++k) {
        float a[4], w[8];
        *(float4*)&a[0] = *(const float4*)&UsT[k][r0];
        *(float4*)&w[0] = *(const float4*)&Wem[k][c0];
        *(float4*)&w[4] = *(const float4*)&Wem[k][c0 + 4];
        #pragma unroll
        for (int i = 0; i < 4; ++i)
            #pragma unroll
            for (int j = 0; j < 8; ++j)
                acc[i][j] += a[i] * w[j];
    }

    #pragma unroll
    for (int i = 0; i < 4; ++i) {
        int n = base + r0 + i;
        if (n < N_NODES) {
            *(float4*)&out[(size_t)n * 128 + c0]     = *(float4*)&acc[i][0];
            *(float4*)&out[(size_t)n * 128 + c0 + 4] = *(float4*)&acc[i][4];
        }
    }
}

extern "C" void kernel_launch(void* const* d_in, const int* in_sizes, int n_in,
                              void* d_out, int out_size, void* d_ws, size_t ws_size,
                              hipStream_t stream) {
    const float* x     = (const float*)d_in[0];
    const float* ef    = (const float*)d_in[1];
    const int*   src   = (const int*)d_in[2];
    const int*   dst   = (const int*)d_in[3];
    const float* W_nl1 = (const float*)d_in[4];
    const float* b_nl1 = (const float*)d_in[5];
    const float* W_el  = (const float*)d_in[6];
    const float* b_el  = (const float*)d_in[7];
    const float* W1    = (const float*)d_in[8];
    const float* b1    = (const float*)d_in[9];
    const float* W2    = (const float*)d_in[10];
    const float* b2    = (const float*)d_in[11];
    const float* W_nl2 = (const float*)d_in[12];
    const float* b_nl2 = (const float*)d_in[13];
    const float* W_ml  = (const float*)d_in[14];
    const float* b_ml  = (const float*)d_in[15];
    const float* W_em  = (const float*)d_in[16];
    const float* b_em  = (const float*)d_in[17];

    int*   wsI = (int*)d_ws;
    float* wsF = (float*)d_ws;
    float* PA     = wsF + WF_PA;
    float* es     = wsF + WF_ES;
    float* u_part = wsF + WF_UP;
    float* uN     = wsF + WF_UN;
    int*   cnt    = wsI + WI_CNT;
    int*   offs   = wsI + WI_OFF;
    int*   cursor = wsI + WI_CUR;
    int*   bsum   = wsI + WI_BSUM;
    int*   boff   = wsI + WI_BOFF;
    int2*  epair  = (int2*)(wsI + WI_EPAIR);
    float* T2   = wsF + WF_T2;
    float* be_g = wsF + WF_BEG;
    float* rh_g = wsF + WF_RH;
    float* K1   = wsF + WF_K1;
    float* WAX  = wsF + WF_WAX;
    float* WE   = wsF + WF_WE;
    float* r    = wsF + WF_R;
    float* c2   = wsF + WF_C2;

    // precompute chain (tiny) + CSR build, interleaved (independent streams)
    pre_t2_kernel<<<17, 256, 0, stream>>>(W2, W_ml, b1, b2, T2, be_g);
    zero_kernel<<<NBLK_SCAN, 256, 0, stream>>>(cnt);
    pre_k1_kernel<<<16, 256, 0, stream>>>(W1, T2, K1);
    hist_kernel<<<(N_EDGES + 255) / 256, 256, 0, stream>>>(dst, cnt);
    pre_wa_kernel<<<97, 256, 0, stream>>>(W_nl1, W_el, W_nl2, K1,
                                          b_nl1, b_el, be_g, W_ml, WAX, WE, rh_g);
    scan_a_kernel<<<NBLK_SCAN, 256, 0, stream>>>(cnt, bsum);
    scan_b_kernel<<<1, 256, 0, stream>>>(bsum, boff);
    scan_c_kernel<<<NBLK_SCAN, 256, 0, stream>>>(cnt, boff, offs, cursor);
    pre_rc_kernel<<<1, 256, 0, stream>>>(rh_g, W_em, b_nl2, b_ml, b_em, r, c2);
    fill_kernel<<<(N_EDGES + 255) / 256, 256, 0, stream>>>(dst, src, cursor, epair);

    // PA = x @ [W_nl2 | W_nl1@K1]
    pa_kernel<<<(N_NODES + 127) / 128, 256, 0, stream>>>(x, WAX, PA);

    // gather: one wave per node, paired half-wave loads
    gather_kernel<<<(N_NODES + 3) / 4, 256, 0, stream>>>(
        PA, ef, cnt, offs, epair, es, u_part);

    gemm1_kernel<<<(N_NODES + 127) / 128, 256, 0, stream>>>(es, u_part, WE, uN);
    gemm2_kernel<<<(N_NODES + 63) / 64, 256, 0, stream>>>(
        uN, cnt, W_em, r, c2, (float*)d_out);
}